// Round 13
// baseline (47.129 us; speedup 1.0000x reference)
//
#include <hip/hip_runtime.h>

// ChamferDistance: B=4, N=M=8192, fp32 3-D points.
// R13: A-side reuse x2. R5/R10/R11/R12 all pinned at 37.1-37.8 µs while
// prefetch depth (1/4/8) and VALU count (fmin vs min3) changed NOTHING ->
// instruction-stream theories falsified. Last invariant: per-CU global-load
// bytes (every wave privately streams 64 KB of B; 1 MB/CU through the TA/L1
// path). This round: each wave owns 128 rows (afrag0..3), so each B tile
// feeds 4 MFMAs -> per-wave B 64->32 KB, device 256->128 MB, per-CU 512 KB.
// If the vector-memory path was the ~35 µs limit, time ~halves; if it stays
// ~37.7, the number is a measurement floor, not kernel time.
// Geometry: ROWBLK=16 (512 rows/block), NCHUNK=8 (1024 cols/chunk), grid
// still 1024 = 4 blocks/CU = 4 waves/SIMD.
// Registers (mis-counted twice before, conservative now): afrag 16 + rmin 64
// + bf 8 + one acc 16 + addr ~12 = ~116 < 128 cap at (256,4). Sequential acc
// (produced then immediately min'd), NO pairing, depth-2 load pipeline.
// Math unchanged (verified since R4, absmax 0.0156).

typedef short  short8 __attribute__((ext_vector_type(8)));
typedef float  f32x16 __attribute__((ext_vector_type(16)));

#define B_      4
#define NPT     8192
#define THREADS 256
#define ROWBLK  16               // 512-row blocks per (pass, batch)
#define NCHUNK  8                // col chunks -> grid = 2*4*16*8 = 1024 = 4/CU
#define CCOLS   (NPT / NCHUNK)   // 1024 cols per chunk
#define NTILE   (CCOLS / 32)     // 32 32-col tiles per chunk
#define PINF_I  0x7f800000

__device__ __forceinline__ unsigned short f2bf(float x) {
    unsigned u = __float_as_uint(x);
    u += 0x7fff + ((u >> 16) & 1);
    return (unsigned short)(u >> 16);
}
__device__ __forceinline__ float bf2f(unsigned short b) {
    return __uint_as_float(((unsigned)b) << 16);
}
#define PK2(a, b) ((((unsigned)(b)) << 16) | (unsigned)(a))

__global__ __launch_bounds__(THREADS)
void cd_pack(const float* __restrict__ xyz1, const float* __restrict__ xyz2,
             unsigned short* __restrict__ A1, unsigned short* __restrict__ B1,
             unsigned short* __restrict__ A2, unsigned short* __restrict__ B2,
             int* __restrict__ out) {
    int i = blockIdx.x * THREADS + threadIdx.x;
    if (i >= B_ * NPT) return;
    const unsigned short one = 0x3f80;

    // B-form split-K placement: group g = i>>5, slot = i&31.
    //   uint4 idx for k0..7  : g*64 + slot ; k8..15 : g*64 + 32 + slot
    const size_t bidx = ((size_t)(i >> 5)) * 64 + (i & 31);

    {   // cloud 1 -> A1 (linear) + B1 (split-K)
        float x0 = xyz1[3*i], x1 = xyz1[3*i+1], x2 = xyz1[3*i+2];
        unsigned short h0 = f2bf(x0), h1 = f2bf(x1), h2 = f2bf(x2);
        unsigned short l0 = f2bf(x0 - bf2f(h0)), l1 = f2bf(x1 - bf2f(h1)), l2 = f2bf(x2 - bf2f(h2));
        unsigned short m0 = f2bf(-2.f * bf2f(h0)), m1 = f2bf(-2.f * bf2f(h1)), m2 = f2bf(-2.f * bf2f(h2));
        unsigned short q0 = f2bf(-2.f * bf2f(l0)), q1 = f2bf(-2.f * bf2f(l1)), q2 = f2bf(-2.f * bf2f(l2));
        float n = x0*x0 + x1*x1 + x2*x2;
        unsigned short nh = f2bf(n), nl = f2bf(n - bf2f(nh));
        ((uint4*)A1)[(size_t)i * 2]     = make_uint4(PK2(m0, m1), PK2(m2, q0), PK2(q1, q2), PK2(m0, m1));
        ((uint4*)A1)[(size_t)i * 2 + 1] = make_uint4(PK2(m2, nh), PK2(nl, one), PK2(one, 0), PK2(0, 0));
        ((uint4*)B1)[bidx]      = make_uint4(PK2(h0, h1), PK2(h2, h0), PK2(h1, h2), PK2(l0, l1));
        ((uint4*)B1)[bidx + 32] = make_uint4(PK2(l2, one), PK2(one, nh), PK2(nl, 0), PK2(0, 0));
    }
    {   // cloud 2 -> A2 (linear) + B2 (split-K)
        float x0 = xyz2[3*i], x1 = xyz2[3*i+1], x2 = xyz2[3*i+2];
        unsigned short h0 = f2bf(x0), h1 = f2bf(x1), h2 = f2bf(x2);
        unsigned short l0 = f2bf(x0 - bf2f(h0)), l1 = f2bf(x1 - bf2f(h1)), l2 = f2bf(x2 - bf2f(h2));
        unsigned short m0 = f2bf(-2.f * bf2f(h0)), m1 = f2bf(-2.f * bf2f(h1)), m2 = f2bf(-2.f * bf2f(h2));
        unsigned short q0 = f2bf(-2.f * bf2f(l0)), q1 = f2bf(-2.f * bf2f(l1)), q2 = f2bf(-2.f * bf2f(l2));
        float n = x0*x0 + x1*x1 + x2*x2;
        unsigned short nh = f2bf(n), nl = f2bf(n - bf2f(nh));
        ((uint4*)A2)[(size_t)i * 2]     = make_uint4(PK2(m0, m1), PK2(m2, q0), PK2(q1, q2), PK2(m0, m1));
        ((uint4*)A2)[(size_t)i * 2 + 1] = make_uint4(PK2(m2, nh), PK2(nl, one), PK2(one, 0), PK2(0, 0));
        ((uint4*)B2)[bidx]      = make_uint4(PK2(h0, h1), PK2(h2, h0), PK2(h1, h2), PK2(l0, l1));
        ((uint4*)B2)[bidx + 32] = make_uint4(PK2(l2, one), PK2(one, nh), PK2(nl, 0), PK2(0, 0));
    }
    out[i] = PINF_I;
    out[(size_t)B_ * NPT + i] = PINF_I;
}

// Compute one B tile against all 4 row-tiles; acc produced then immediately
// consumed (one 16-reg acc live at a time).
#define CD_TILE(bf)                                                              \
    {                                                                            \
        f32x16 z = {0.f};                                                        \
        f32x16 acc;                                                              \
        acc = __builtin_amdgcn_mfma_f32_32x32x16_bf16(afrag0, bf, z, 0, 0, 0);   \
        _Pragma("unroll")                                                        \
        for (int r = 0; r < 16; ++r) rmin0[r] = fminf(rmin0[r], acc[r]);         \
        acc = __builtin_amdgcn_mfma_f32_32x32x16_bf16(afrag1, bf, z, 0, 0, 0);   \
        _Pragma("unroll")                                                        \
        for (int r = 0; r < 16; ++r) rmin1[r] = fminf(rmin1[r], acc[r]);         \
        acc = __builtin_amdgcn_mfma_f32_32x32x16_bf16(afrag2, bf, z, 0, 0, 0);   \
        _Pragma("unroll")                                                        \
        for (int r = 0; r < 16; ++r) rmin2[r] = fminf(rmin2[r], acc[r]);         \
        acc = __builtin_amdgcn_mfma_f32_32x32x16_bf16(afrag3, bf, z, 0, 0, 0);   \
        _Pragma("unroll")                                                        \
        for (int r = 0; r < 16; ++r) rmin3[r] = fminf(rmin3[r], acc[r]);         \
    }

// Reload one bf register with tile index tn (clamped; tail re-reads last tile
// harmlessly — min is idempotent).
#define CD_LOAD(bf, tn)                                                          \
    {                                                                            \
        int tt = (tn) < NTILE ? (tn) : NTILE - 1;                                \
        bf = *(const short8*)(gB + (size_t)tt * 512);                            \
    }

__global__ __launch_bounds__(THREADS, 4)    // live ~116 regs < 128 cap
void cd_mfma32(const unsigned short* __restrict__ A1, const unsigned short* __restrict__ B1,
               const unsigned short* __restrict__ A2, const unsigned short* __restrict__ B2,
               int* __restrict__ out) {
    int bid = blockIdx.x;
    const int c    = bid & (NCHUNK - 1);  bid >>= 3;   // 8 chunks
    const int rb   = bid & (ROWBLK - 1);  bid >>= 4;   // 16 row-blocks
    const int b    = bid & (B_ - 1);      bid >>= 2;
    const int pass = bid;                               // 0: dist1, 1: dist2

    const unsigned short* __restrict__ Ap = pass ? A2 : A1;
    const unsigned short* __restrict__ Bp = pass ? B1 : B2;
    int* __restrict__ o = out + (size_t)pass * B_ * NPT;

    const int lane = threadIdx.x & 63;
    const int w    = threadIdx.x >> 6;
    const int l31  = lane & 31;
    const int kg   = lane >> 5;            // k-half: k = kg*8 + idx

    const size_t bbase   = (size_t)b * NPT;
    const int    rowBase = rb * 512 + w * 128;   // 128 rows per wave

    // A fragments: 4 row-tiles x 32 rows, resident for the whole sweep
    short8 afrag0 = *(const short8*)(Ap + (bbase + rowBase +  0 + l31) * 16 + kg * 8);
    short8 afrag1 = *(const short8*)(Ap + (bbase + rowBase + 32 + l31) * 16 + kg * 8);
    short8 afrag2 = *(const short8*)(Ap + (bbase + rowBase + 64 + l31) * 16 + kg * 8);
    short8 afrag3 = *(const short8*)(Ap + (bbase + rowBase + 96 + l31) * 16 + kg * 8);

    f32x16 rmin0, rmin1, rmin2, rmin3;
    #pragma unroll
    for (int r = 0; r < 16; ++r) {
        rmin0[r] = __int_as_float(PINF_I);
        rmin1[r] = __int_as_float(PINF_I);
        rmin2[r] = __int_as_float(PINF_I);
        rmin3[r] = __int_as_float(PINF_I);
    }

    // B chunk base, split-K: 32-pt group = 512 ushorts; lane reads
    // kg*256 + l31*8 -> each wave instruction covers a contiguous 1 KB.
    const unsigned short* __restrict__ gB =
        Bp + (bbase + (size_t)c * CCOLS) * 16 + kg * 256 + l31 * 8;

    // Depth-2 pipeline: consume one tile while the other loads.
    short8 bfA, bfB;
    CD_LOAD(bfA, 0)
    CD_LOAD(bfB, 1)

    for (int t = 0; t < NTILE; t += 2) {
        CD_TILE(bfA)
        CD_LOAD(bfA, t + 2)
        CD_TILE(bfB)
        CD_LOAD(bfB, t + 3)
    }

    // Epilogue: butterfly row-mins across 32 col-slots, one atomic per row
    #pragma unroll
    for (int rt = 0; rt < 4; ++rt) {
        #pragma unroll
        for (int r = 0; r < 16; ++r) {
            float v = rt == 0 ? rmin0[r] : rt == 1 ? rmin1[r] : rt == 2 ? rmin2[r] : rmin3[r];
            v = fminf(v, __shfl_xor(v, 1, 64));
            v = fminf(v, __shfl_xor(v, 2, 64));
            v = fminf(v, __shfl_xor(v, 4, 64));
            v = fminf(v, __shfl_xor(v, 8, 64));
            v = fminf(v, __shfl_xor(v, 16, 64));
            if (l31 == 0) {
                int row = rowBase + rt * 32 + (r & 3) + 8 * (r >> 2) + 4 * kg;
                atomicMin(&o[bbase + row], __float_as_int(fmaxf(v, 0.f)));
            }
        }
    }
}

extern "C" void kernel_launch(void* const* d_in, const int* in_sizes, int n_in,
                              void* d_out, int out_size, void* d_ws, size_t ws_size,
                              hipStream_t stream) {
    const float* xyz1 = (const float*)d_in[0];
    const float* xyz2 = (const float*)d_in[1];

    const size_t PSZ = (size_t)B_ * NPT * 16;       // ushorts per packed array
    unsigned short* A1 = (unsigned short*)d_ws;     // 4 x 1 MB in d_ws
    unsigned short* B1 = A1 + PSZ;
    unsigned short* A2 = B1 + PSZ;
    unsigned short* B2 = A2 + PSZ;

    cd_pack<<<(B_ * NPT + THREADS - 1) / THREADS, THREADS, 0, stream>>>(
        xyz1, xyz2, A1, B1, A2, B2, (int*)d_out);

    cd_mfma32<<<2 * B_ * ROWBLK * NCHUNK, THREADS, 0, stream>>>(
        A1, B1, A2, B2, (int*)d_out);
}

// Round 14
// 40.351 us; speedup vs baseline: 1.1680x; 1.1680x over previous
//
#include <hip/hip_runtime.h>

// ChamferDistance: B=4, N=M=8192, fp32 3-D points.
// R14: whole-chunk LDS staging, ONE barrier per block.
// R13 post-mortem: occupancy counter says every MFMA variant ran at ~2
// waves/SIMD (VGPR_Count hides the AGPR half of the unified file), and with
// the compiler sinking named-reg loads to depth-1, in-loop L2 latency under
// load (~800 cyc) was exposed serially -> the invariant ~34 µs floor.
// Fix: no global loads in the loop at all. Each block stages its whole
// 32 KB B-chunk via global_load_lds (8x16B per thread), one __syncthreads,
// then 32 tiles of pure LDS compute (ds_read latency ~120 cyc, fixed,
// covered by 4 waves/SIMD). Differs from the failed R9 in exactly the three
// killers: 1 barrier/chunk (not per 256 cols), 32 KB LDS -> 4 blocks/CU
// (not 2), and the R5 compute shape proven to fit the 128-reg bucket
// (36 VGPR + ~32 AGPR). Side effect: global B traffic 256 -> 64 MB.
// Math unchanged (verified since R4, absmax 0.0156):
//   A-form(p): [-2ph(3), -2pl(3), -2ph(3), nh, nl, 1, 1, 0,0,0]  (K=16)
//   B-form(p): [  ph(3),   ph(3),   pl(3),  1,  1, nh, nl, 0,0,0]
// B stored split-K per 32-pt group (32x16B k0..7 then 32x16B k8..15):
// LDS reads are contiguous 16 B/lane -> conflict-free (m134 pattern).

typedef short  short8 __attribute__((ext_vector_type(8)));
typedef float  f32x16 __attribute__((ext_vector_type(16)));

#define B_      4
#define NPT     8192
#define THREADS 256
#define NROWBLK 32               // 8192/256 row-blocks (256 rows per block)
#define NCHUNK  8                // col chunks -> grid = 2*4*32*8 = 2048
#define CCOLS   (NPT / NCHUNK)   // 1024 cols per chunk
#define NTILE   (CCOLS / 32)     // 32 32-col tiles per chunk
#define CHUNKUS (CCOLS * 16)     // 16384 ushorts = 32 KB per chunk
#define PINF_I  0x7f800000

__device__ __forceinline__ unsigned short f2bf(float x) {
    unsigned u = __float_as_uint(x);
    u += 0x7fff + ((u >> 16) & 1);
    return (unsigned short)(u >> 16);
}
__device__ __forceinline__ float bf2f(unsigned short b) {
    return __uint_as_float(((unsigned)b) << 16);
}
#define PK2(a, b) ((((unsigned)(b)) << 16) | (unsigned)(a))

__global__ __launch_bounds__(THREADS)
void cd_pack(const float* __restrict__ xyz1, const float* __restrict__ xyz2,
             unsigned short* __restrict__ A1, unsigned short* __restrict__ B1,
             unsigned short* __restrict__ A2, unsigned short* __restrict__ B2,
             int* __restrict__ out) {
    int i = blockIdx.x * THREADS + threadIdx.x;
    if (i >= B_ * NPT) return;
    const unsigned short one = 0x3f80;

    // B-form split-K placement: group g = i>>5, slot = i&31.
    //   uint4 idx for k0..7  : g*64 + slot ; k8..15 : g*64 + 32 + slot
    const size_t bidx = ((size_t)(i >> 5)) * 64 + (i & 31);

    {   // cloud 1 -> A1 (linear) + B1 (split-K)
        float x0 = xyz1[3*i], x1 = xyz1[3*i+1], x2 = xyz1[3*i+2];
        unsigned short h0 = f2bf(x0), h1 = f2bf(x1), h2 = f2bf(x2);
        unsigned short l0 = f2bf(x0 - bf2f(h0)), l1 = f2bf(x1 - bf2f(h1)), l2 = f2bf(x2 - bf2f(h2));
        unsigned short m0 = f2bf(-2.f * bf2f(h0)), m1 = f2bf(-2.f * bf2f(h1)), m2 = f2bf(-2.f * bf2f(h2));
        unsigned short q0 = f2bf(-2.f * bf2f(l0)), q1 = f2bf(-2.f * bf2f(l1)), q2 = f2bf(-2.f * bf2f(l2));
        float n = x0*x0 + x1*x1 + x2*x2;
        unsigned short nh = f2bf(n), nl = f2bf(n - bf2f(nh));
        ((uint4*)A1)[(size_t)i * 2]     = make_uint4(PK2(m0, m1), PK2(m2, q0), PK2(q1, q2), PK2(m0, m1));
        ((uint4*)A1)[(size_t)i * 2 + 1] = make_uint4(PK2(m2, nh), PK2(nl, one), PK2(one, 0), PK2(0, 0));
        ((uint4*)B1)[bidx]      = make_uint4(PK2(h0, h1), PK2(h2, h0), PK2(h1, h2), PK2(l0, l1));
        ((uint4*)B1)[bidx + 32] = make_uint4(PK2(l2, one), PK2(one, nh), PK2(nl, 0), PK2(0, 0));
    }
    {   // cloud 2 -> A2 (linear) + B2 (split-K)
        float x0 = xyz2[3*i], x1 = xyz2[3*i+1], x2 = xyz2[3*i+2];
        unsigned short h0 = f2bf(x0), h1 = f2bf(x1), h2 = f2bf(x2);
        unsigned short l0 = f2bf(x0 - bf2f(h0)), l1 = f2bf(x1 - bf2f(h1)), l2 = f2bf(x2 - bf2f(h2));
        unsigned short m0 = f2bf(-2.f * bf2f(h0)), m1 = f2bf(-2.f * bf2f(h1)), m2 = f2bf(-2.f * bf2f(h2));
        unsigned short q0 = f2bf(-2.f * bf2f(l0)), q1 = f2bf(-2.f * bf2f(l1)), q2 = f2bf(-2.f * bf2f(l2));
        float n = x0*x0 + x1*x1 + x2*x2;
        unsigned short nh = f2bf(n), nl = f2bf(n - bf2f(nh));
        ((uint4*)A2)[(size_t)i * 2]     = make_uint4(PK2(m0, m1), PK2(m2, q0), PK2(q1, q2), PK2(m0, m1));
        ((uint4*)A2)[(size_t)i * 2 + 1] = make_uint4(PK2(m2, nh), PK2(nl, one), PK2(one, 0), PK2(0, 0));
        ((uint4*)B2)[bidx]      = make_uint4(PK2(h0, h1), PK2(h2, h0), PK2(h1, h2), PK2(l0, l1));
        ((uint4*)B2)[bidx + 32] = make_uint4(PK2(l2, one), PK2(one, nh), PK2(nl, 0), PK2(0, 0));
    }
    out[i] = PINF_I;
    out[(size_t)B_ * NPT + i] = PINF_I;
}

__global__ __launch_bounds__(THREADS, 4)    // R5 compute shape: ~94 unified regs
void cd_mfma32(const unsigned short* __restrict__ A1, const unsigned short* __restrict__ B1,
               const unsigned short* __restrict__ A2, const unsigned short* __restrict__ B2,
               int* __restrict__ out) {
    __shared__ unsigned short ysh[CHUNKUS];           // 32 KB, staged once

    int bid = blockIdx.x;
    const int c    = bid & (NCHUNK - 1);   bid >>= 3;  // 8 chunks
    const int rb   = bid & (NROWBLK - 1);  bid >>= 5;  // 32 row-blocks
    const int b    = bid & (B_ - 1);       bid >>= 2;
    const int pass = bid;                               // 0: dist1, 1: dist2

    const unsigned short* __restrict__ Ap = pass ? A2 : A1;
    const unsigned short* __restrict__ Bp = pass ? B1 : B2;
    int* __restrict__ o = out + (size_t)pass * B_ * NPT;

    const int lane = threadIdx.x & 63;
    const int w    = threadIdx.x >> 6;
    const int l31  = lane & 31;
    const int kg   = lane >> 5;            // k-half: k = kg*8 + idx

    const size_t bbase   = (size_t)b * NPT;
    const int    rowBase = rb * 256 + w * 64;

    // A fragments first (their latency overlaps the LDS staging below)
    short8 afrag0 = *(const short8*)(Ap + (bbase + rowBase +  0 + l31) * 16 + kg * 8);
    short8 afrag1 = *(const short8*)(Ap + (bbase + rowBase + 32 + l31) * 16 + kg * 8);

    // Stage the whole 32 KB chunk: 8 x global_load_lds(16B) per thread.
    // LDS dest = wave-uniform base + lane*16 (linear copy, layout-agnostic).
    {
        const unsigned short* gC = Bp + bbase * 16 + (size_t)c * CHUNKUS;
        #pragma unroll
        for (int r = 0; r < 8; ++r) {
            const unsigned short* gp = gC + r * 2048 + w * 512 + lane * 8;
            unsigned short* lp = &ysh[r * 2048 + w * 512];
            __builtin_amdgcn_global_load_lds(
                (const __attribute__((address_space(1))) unsigned int*)gp,
                (__attribute__((address_space(3))) unsigned int*)lp, 16, 0, 0);
        }
    }

    f32x16 rmin0, rmin1;
    #pragma unroll
    for (int r = 0; r < 16; ++r) {
        rmin0[r] = __int_as_float(PINF_I);
        rmin1[r] = __int_as_float(PINF_I);
    }

    __syncthreads();   // the ONLY barrier: drains staging vmcnt, then pure LDS

    // 32 tiles: 1 conflict-free ds_read_b128 + 2 MFMA + 32 fmin each.
    #pragma unroll 4
    for (int t = 0; t < NTILE; ++t) {
        short8 bf = *(const short8*)(&ysh[t * 512 + kg * 256 + l31 * 8]);
        f32x16 z = {0.f};
        f32x16 acc0 = __builtin_amdgcn_mfma_f32_32x32x16_bf16(afrag0, bf, z, 0, 0, 0);
        #pragma unroll
        for (int r = 0; r < 16; ++r) rmin0[r] = fminf(rmin0[r], acc0[r]);
        f32x16 acc1 = __builtin_amdgcn_mfma_f32_32x32x16_bf16(afrag1, bf, z, 0, 0, 0);
        #pragma unroll
        for (int r = 0; r < 16; ++r) rmin1[r] = fminf(rmin1[r], acc1[r]);
    }

    // Epilogue: butterfly row-mins across 32 col-slots, one atomic per row
    #pragma unroll
    for (int rt = 0; rt < 2; ++rt) {
        #pragma unroll
        for (int r = 0; r < 16; ++r) {
            float v = rt ? rmin1[r] : rmin0[r];
            v = fminf(v, __shfl_xor(v, 1, 64));
            v = fminf(v, __shfl_xor(v, 2, 64));
            v = fminf(v, __shfl_xor(v, 4, 64));
            v = fminf(v, __shfl_xor(v, 8, 64));
            v = fminf(v, __shfl_xor(v, 16, 64));
            if (l31 == 0) {
                int row = rowBase + rt * 32 + (r & 3) + 8 * (r >> 2) + 4 * kg;
                atomicMin(&o[bbase + row], __float_as_int(fmaxf(v, 0.f)));
            }
        }
    }
}

extern "C" void kernel_launch(void* const* d_in, const int* in_sizes, int n_in,
                              void* d_out, int out_size, void* d_ws, size_t ws_size,
                              hipStream_t stream) {
    const float* xyz1 = (const float*)d_in[0];
    const float* xyz2 = (const float*)d_in[1];

    const size_t PSZ = (size_t)B_ * NPT * 16;       // ushorts per packed array
    unsigned short* A1 = (unsigned short*)d_ws;     // 4 x 1 MB in d_ws
    unsigned short* B1 = A1 + PSZ;
    unsigned short* A2 = B1 + PSZ;
    unsigned short* B2 = A2 + PSZ;

    cd_pack<<<(B_ * NPT + THREADS - 1) / THREADS, THREADS, 0, stream>>>(
        xyz1, xyz2, A1, B1, A2, B2, (int*)d_out);

    cd_mfma32<<<2 * B_ * NROWBLK * NCHUNK, THREADS, 0, stream>>>(
        A1, B1, A2, B2, (int*)d_out);
}